// Round 11
// baseline (446.573 us; speedup 1.0000x reference)
//
#include <hip/hip_runtime.h>
#include <math.h>

// ---------------------------------------------------------------------------
// RFSQDraftModelWithProjection — f32 in / f32 out, bf16 MFMA compute.
// r11: counted-vmcnt pipeline (T4): never vmcnt(0) in the K-loop; raw
// s_barrier pairs; prefetch loads stay in flight across barriers.
//
// Algebra: seq_len==1 => attention == out_proj(V(.)):
//   h2 = h0 + [h0 | ln1(h0)] @ Wct + b_comb,  Wct = [wv_ca@wo_ca ; wv_sa@wo_sa]
// ---------------------------------------------------------------------------

typedef unsigned short u16;
typedef __attribute__((ext_vector_type(8))) short bf16x8;
typedef __attribute__((ext_vector_type(4))) float f32x4;
typedef __attribute__((ext_vector_type(8))) unsigned short u16x8;
typedef __attribute__((ext_vector_type(4))) unsigned short u16x4;

__device__ __forceinline__ float bf2f(u16 u){
    union { unsigned int i; float f; } x; x.i = ((unsigned int)u) << 16; return x.f;
}
__device__ __forceinline__ u16 f2bf(float f){
    union { float f; unsigned int i; } x; x.f = f;
    unsigned int r = x.i + 0x7fffu + ((x.i >> 16) & 1u);
    return (u16)(r >> 16);
}
__device__ __forceinline__ float gelu_exact(float v){
    return 0.5f * v * (1.0f + erff(v * 0.7071067811865475f));
}
#define GLOAD16(src, dst) __builtin_amdgcn_global_load_lds( \
    (const __attribute__((address_space(1))) void*)(src),   \
    (__attribute__((address_space(3))) void*)(dst), 16, 0, 0)
#define SCHED0 __builtin_amdgcn_sched_barrier(0)

// ---------------------------------------------------------------------------
// GEMM: C[M,N] = A[M,K] @ B[K,N] (+bias +res, opt GELU).  64x128 tile, BK=32,
// 4 waves (2x2, each 32x64), mfma_f32_16x16x32_bf16.
// Counted-vmcnt double buffer: per K-step issue next tile's loads, wait
// vmcnt(L) (L = this step's issue count -> drains only previous tile's),
// raw s_barrier, ds_read+MFMA, second s_barrier. No vmcnt(0) until the end.
// A: AF32=1 -> f32 reg-staged+cvt (loads issued FIRST so the compiler's wait
// before writeA is counted, not a drain); else bf16 via global_load_lds.
// A2/ksplit: k0>=ksplit reads A2 (fuses attention K=1024).
// z-batch: per-blockIdx.z strides azs/bzs/biaszs/czs (elements).
// M%64==0, N%128==0, K%32==0.  In-place residual (res==C) safe.
// ---------------------------------------------------------------------------
template<bool GELU, bool RES, bool AF32, bool OUTF32>
__global__ __launch_bounds__(256) void gemm64(
    const void* __restrict__ A, const void* __restrict__ A2, int ksplit,
    const u16* __restrict__ Bt, const float* __restrict__ bias,
    const u16* __restrict__ res, int ldr,
    void* __restrict__ Cout, int K, int lda, int ldb, int ldc,
    long azs, long bzs, int biaszs, long czs)
{
    __shared__ __align__(16) u16 As[2][64 * 32];
    __shared__ __align__(16) u16 Bs[2][128 * 32];
    const int tid = threadIdx.x;
    const int w = tid >> 6, l = tid & 63;
    const int wr = w >> 1, wc = w & 1;
    const int m0 = blockIdx.y * 64, n0 = blockIdx.x * 128;
    const int z = blockIdx.z;
    const u16* A16 = (const u16*)A + (size_t)z * azs;
    const float* Af = (const float*)A;
    const u16* BtZ = Bt + (size_t)z * bzs;

    f32x4 acc[2][4];
#pragma unroll
    for (int i = 0; i < 2; ++i)
#pragma unroll
        for (int j = 0; j < 4; ++j) acc[i][j] = (f32x4){0.f, 0.f, 0.f, 0.f};

    float4 pa0, pa1;  // AF32 pending regs
    auto stageB = [&](int buf, int k0) {
#pragma unroll
        for (int j = 0; j < 2; ++j) {
            const u16* gb = BtZ + (size_t)(n0 + (w * 2 + j) * 16 + (l >> 2)) * ldb
                          + k0 + (l & 3) * 8;
            GLOAD16(gb, &Bs[buf][(w * 2 + j) * 512]);
        }
    };
    auto stageA16 = [&](int buf, int k0) {
        const u16* base = (k0 >= ksplit) ? ((const u16*)A2 + (k0 - ksplit)) : (A16 + k0);
        const u16* ga = base + (size_t)(m0 + w * 16 + (l >> 2)) * lda + (l & 3) * 8;
        GLOAD16(ga, &As[buf][w * 512]);
    };
    auto loadA = [&](int k0) {
        const float* g = Af + (size_t)(m0 + (tid >> 2)) * lda + k0 + (tid & 3) * 8;
        pa0 = *(const float4*)g; pa1 = *(const float4*)(g + 4);
    };
    auto writeA = [&](int buf) {
        u16x8 v;
        v[0] = f2bf(pa0.x); v[1] = f2bf(pa0.y); v[2] = f2bf(pa0.z); v[3] = f2bf(pa0.w);
        v[4] = f2bf(pa1.x); v[5] = f2bf(pa1.y); v[6] = f2bf(pa1.z); v[7] = f2bf(pa1.w);
        *(u16x8*)&As[buf][(tid >> 2) * 32 + (tid & 3) * 8] = v;
    };

    const int nt = K >> 5;
    // prologue: tile 0 (A-loads first; writeA's compiler wait = counted)
    if (AF32) loadA(0); else stageA16(0, 0);
    stageB(0, 0);
    if (AF32) writeA(0);
    int cur = 0;
    for (int t = 0; t < nt; ++t) {
        const bool more = (t + 1) < nt;
        if (more) {
            if (AF32) loadA((t + 1) << 5);
            else stageA16(cur ^ 1, (t + 1) << 5);
            stageB(cur ^ 1, (t + 1) << 5);
        }
        // drain only the PREVIOUS tile's loads; this tile's stay in flight
        if (more) {
            if (AF32) asm volatile("s_waitcnt vmcnt(4) lgkmcnt(0)" ::: "memory");
            else      asm volatile("s_waitcnt vmcnt(3) lgkmcnt(0)" ::: "memory");
        } else {
            asm volatile("s_waitcnt vmcnt(0) lgkmcnt(0)" ::: "memory");
        }
        SCHED0;
        __builtin_amdgcn_s_barrier();
        SCHED0;
        bf16x8 a[2], b[4];
#pragma unroll
        for (int i = 0; i < 2; ++i)
            a[i] = *(const bf16x8*)&As[cur][(wr * 32 + i * 16 + (l & 15)) * 32 + (l >> 4) * 8];
#pragma unroll
        for (int j = 0; j < 4; ++j)
            b[j] = *(const bf16x8*)&Bs[cur][(wc * 64 + j * 16 + (l & 15)) * 32 + (l >> 4) * 8];
#pragma unroll
        for (int i = 0; i < 2; ++i)
#pragma unroll
            for (int j = 0; j < 4; ++j)
                acc[i][j] = __builtin_amdgcn_mfma_f32_16x16x32_bf16(a[i], b[j], acc[i][j], 0, 0, 0);
        if (AF32 && more) writeA(cur ^ 1);
        asm volatile("" ::: "memory");
        SCHED0;
        __builtin_amdgcn_s_barrier();
        SCHED0;
        cur ^= 1;
    }

    // epilogue: C/D layout col = l&15, row = (l>>4)*4 + r  [m89/m91]
    float* cF = (float*)Cout + (size_t)z * czs;
    u16*   cH = (u16*)Cout + (size_t)z * czs;
    const float* biasZ = bias ? bias + (size_t)z * biaszs : nullptr;
#pragma unroll
    for (int i = 0; i < 2; ++i) {
#pragma unroll
        for (int j = 0; j < 4; ++j) {
            const int col = n0 + wc * 64 + j * 16 + (l & 15);
            const int rowb = m0 + wr * 32 + i * 16 + (l >> 4) * 4;
#pragma unroll
            for (int r = 0; r < 4; ++r) {
                const int row = rowb + r;
                float v = acc[i][j][r];
                if (biasZ) v += biasZ[col];
                if (RES) v += bf2f(res[(size_t)row * ldr + col]);
                if (GELU) v = gelu_exact(v);
                if (OUTF32) cF[(size_t)row * ldc + col] = v;
                else        cH[(size_t)row * ldc + col] = f2bf(v);
            }
        }
    }
}

// f32 -> bf16 bulk convert, 8 elems/thread
__global__ __launch_bounds__(256) void cvt_f32_bf16(
    const float* __restrict__ in, u16* __restrict__ out, int n8)
{
    const int i = blockIdx.x * 256 + threadIdx.x;
    if (i >= n8) return;
    const float4* p = (const float4*)in + (size_t)i * 2;
    const float4 a = p[0], b = p[1];
    u16x8 v;
    v[0] = f2bf(a.x); v[1] = f2bf(a.y); v[2] = f2bf(a.z); v[3] = f2bf(a.w);
    v[4] = f2bf(b.x); v[5] = f2bf(b.y); v[6] = f2bf(b.z); v[7] = f2bf(b.w);
    *(u16x8*)(out + (size_t)i * 8) = v;
}

// LayerNorm over 512 cols (bf16 in/out, f32 g/b), one wave per row
__global__ __launch_bounds__(256) void ln512_kernel(
    const u16* __restrict__ in, const float* __restrict__ g,
    const float* __restrict__ b, u16* __restrict__ out)
{
    const int wid = threadIdx.x >> 6, l = threadIdx.x & 63;
    const size_t row = (size_t)blockIdx.x * 4 + wid;
    u16x8 v = *(const u16x8*)(in + row * 512 + l * 8);
    float f[8], s = 0.f, q = 0.f;
#pragma unroll
    for (int j = 0; j < 8; ++j) { f[j] = bf2f(v[j]); s += f[j]; q += f[j] * f[j]; }
#pragma unroll
    for (int o = 32; o > 0; o >>= 1) { s += __shfl_xor(s, o); q += __shfl_xor(q, o); }
    const float mean = s * (1.f / 512.f);
    const float var = q * (1.f / 512.f) - mean * mean;
    const float rstd = rsqrtf(var + 1e-5f);
    u16x8 ov;
#pragma unroll
    for (int j = 0; j < 8; ++j) {
        const int c = l * 8 + j;
        ov[j] = f2bf((f[j] - mean) * rstd * g[c] + b[c]);
    }
    *(u16x8*)(out + row * 512 + l * 8) = ov;
}

// per-head LN over 256 (rows are [8192,768], heads of 256), wave per (row,head)
__global__ __launch_bounds__(256) void lnh_kernel(
    const u16* __restrict__ in, const float* __restrict__ g,
    const float* __restrict__ b, u16* __restrict__ out)
{
    const int wid = threadIdx.x >> 6, l = threadIdx.x & 63;
    const int unit = blockIdx.x * 4 + wid;        // unit = h*8192 + row
    const int h = unit >> 13, row = unit & 8191;
    const size_t base = (size_t)row * 768 + h * 256 + l * 4;
    u16x4 v = *(const u16x4*)(in + base);
    float f[4], s = 0.f, q = 0.f;
#pragma unroll
    for (int j = 0; j < 4; ++j) { f[j] = bf2f(v[j]); s += f[j]; q += f[j] * f[j]; }
#pragma unroll
    for (int o = 32; o > 0; o >>= 1) { s += __shfl_xor(s, o); q += __shfl_xor(q, o); }
    const float mean = s * (1.f / 256.f);
    const float var = q * (1.f / 256.f) - mean * mean;
    const float rstd = rsqrtf(var + 1e-5f);
    u16x4 ov;
#pragma unroll
    for (int j = 0; j < 4; ++j) {
        const int c = h * 256 + l * 4 + j;
        ov[j] = f2bf((f[j] - mean) * rstd * g[c] + b[c]);
    }
    *(u16x4*)(out + base) = ov;
}

// out[N,K](bf16) = in[K,N](f32)^T, dims % 32 == 0, block = 256 (32x8)
__global__ __launch_bounds__(256) void transpose_kernel(
    const float* __restrict__ in, u16* __restrict__ out, int K, int N)
{
    __shared__ u16 t[32][33];
    const int n0 = blockIdx.x * 32, k0 = blockIdx.y * 32;
    const int tx = threadIdx.x & 31, ty = threadIdx.x >> 5;
#pragma unroll
    for (int i = 0; i < 32; i += 8)
        t[ty + i][tx] = f2bf(in[(size_t)(k0 + ty + i) * N + (n0 + tx)]);
    __syncthreads();
#pragma unroll
    for (int i = 0; i < 32; i += 8)
        out[(size_t)(n0 + ty + i) * K + (k0 + tx)] = t[tx][ty + i];
}

// Wh1t[768][512](bf16): Wh1t[h*256+k][d] = wh1[h][d][k]
__global__ void gather_wh1t(const float* __restrict__ wh1, u16* __restrict__ out)
{
    const int idx = blockIdx.x * 256 + threadIdx.x;
    if (idx >= 768 * 512) return;
    const int d = idx & 511, j = idx >> 9;
    const int h = j >> 8, kk = j & 255;
    out[idx] = f2bf(wh1[((size_t)(h * 512 + d)) * 256 + kk]);
}

// Wh2t[3][896][256](bf16): Wh2t[h][o][k] = wh2[h][k][o]
__global__ void gather_wh2t(const float* __restrict__ wh2, u16* __restrict__ out)
{
    const int idx = blockIdx.x * 256 + threadIdx.x;
    if (idx >= 3 * 896 * 256) return;
    const int kk = idx & 255, t = idx >> 8;
    const int h = t / 896, o = t - h * 896;
    out[idx] = f2bf(wh2[((size_t)(h * 256 + kk)) * 896 + o]);
}

// parallel bias prep: 8 blocks; block b covers i in [b*64, b*64+64).
__global__ __launch_bounds__(256) void prep_bias_kernel(
    const float* __restrict__ b_in, const float* __restrict__ pos,
    const float* __restrict__ bv_sa, const float* __restrict__ wo_sa,
    const float* __restrict__ bo_sa,
    const float* __restrict__ bv_ca, const float* __restrict__ wo_ca,
    const float* __restrict__ bo_ca,
    float* __restrict__ bias_in, float* __restrict__ b_comb)
{
    __shared__ float psa[4][64], pca[4][64];
    const int ii = threadIdx.x & 63, kg = threadIdx.x >> 6;
    const int i = blockIdx.x * 64 + ii;
    float sa = 0.f, ca = 0.f;
    for (int k = kg; k < 512; k += 4) {
        sa += bv_sa[k] * wo_sa[(size_t)k * 512 + i];
        ca += bv_ca[k] * wo_ca[(size_t)k * 512 + i];
    }
    psa[kg][ii] = sa; pca[kg][ii] = ca;
    __syncthreads();
    if (kg == 0) {
        bias_in[i] = b_in[i] + pos[i];
        b_comb[i] = psa[0][ii] + psa[1][ii] + psa[2][ii] + psa[3][ii]
                  + pca[0][ii] + pca[1][ii] + pca[2][ii] + pca[3][ii]
                  + bo_sa[i] + bo_ca[i];
    }
}

extern "C" void kernel_launch(void* const* d_in, const int* in_sizes, int n_in,
                              void* d_out, int out_size, void* d_ws, size_t ws_size,
                              hipStream_t stream)
{
    const float* x      = (const float*)d_in[0];
    const float* w_in   = (const float*)d_in[1];
    const float* b_in   = (const float*)d_in[2];
    const float* pos    = (const float*)d_in[3];
    const float* ln1_g  = (const float*)d_in[4];
    const float* ln1_b  = (const float*)d_in[5];
    const float* wv_sa  = (const float*)d_in[6];
    const float* bv_sa  = (const float*)d_in[7];
    const float* wo_sa  = (const float*)d_in[8];
    const float* bo_sa  = (const float*)d_in[9];
    const float* wv_ca  = (const float*)d_in[12];
    const float* bv_ca  = (const float*)d_in[13];
    const float* wo_ca  = (const float*)d_in[14];
    const float* bo_ca  = (const float*)d_in[15];
    const float* ln3_g  = (const float*)d_in[16];
    const float* ln3_b  = (const float*)d_in[17];
    const float* w_ff1  = (const float*)d_in[18];
    const float* b_ff1  = (const float*)d_in[19];
    const float* w_ff2  = (const float*)d_in[20];
    const float* b_ff2  = (const float*)d_in[21];
    const float* lnoutg = (const float*)d_in[22];
    const float* lnoutb = (const float*)d_in[23];
    const float* wh1    = (const float*)d_in[24];
    const float* bh1    = (const float*)d_in[25];
    const float* lnh_g  = (const float*)d_in[26];
    const float* lnh_b  = (const float*)d_in[27];
    const float* wh2    = (const float*)d_in[28];
    const float* bh2    = (const float*)d_in[29];
    float* out = (float*)d_out;
    const int KBIG = 0x7fffffff;

    // ---- workspace layout (~70 MB, rewritten fully every call) ----
    char* wsp = (char*)d_ws;
    size_t off = 0;
    auto ALLOC = [&](size_t n) { char* r = wsp + off; off = (off + n + 255) & ~(size_t)255; return r; };
    u16* w_inT  = (u16*)ALLOC(512UL * 4096 * 2);
    u16* wff1t  = (u16*)ALLOC(2048UL * 512 * 2);
    u16* wff2t  = (u16*)ALLOC(512UL * 2048 * 2);
    u16* woT2   = (u16*)ALLOC(2UL * 512 * 512 * 2);  // [0]=woTca, [1]=woTsa
    u16* wv2b   = (u16*)ALLOC(2UL * 512 * 512 * 2);  // [0]=wv_ca, [1]=wv_sa
    u16* Wct    = (u16*)ALLOC(512UL * 1024 * 2);     // [n][k] k<512: ca, k>=512: sa
    u16* Wh1t   = (u16*)ALLOC(768UL * 512 * 2);
    u16* Wh2t   = (u16*)ALLOC(3UL * 896 * 256 * 2);
    float* bias_in = (float*)ALLOC(512 * 4);
    float* b_comb  = (float*)ALLOC(512 * 4);
    u16* h0   = (u16*)ALLOC(8192UL * 512 * 2);   // h0, later reused as h3
    u16* T    = (u16*)ALLOC(8192UL * 512 * 2);   // ln1 / ln3 / lnout output
    u16* hbuf = (u16*)ALLOC(8192UL * 512 * 2);   // h2
    u16* G    = (u16*)ALLOC(8192UL * 2048 * 2);  // FF intermediate; Z/Z2 alias
    u16* Z  = G;
    u16* Z2 = (u16*)((char*)G + 8192UL * 768 * 2);

    // ---- weight prep ----
    cvt_f32_bf16<<<128, 256, 0, stream>>>(wv_ca, wv2b, 512 * 512 / 8);
    cvt_f32_bf16<<<128, 256, 0, stream>>>(wv_sa, wv2b + 512 * 512, 512 * 512 / 8);
    prep_bias_kernel<<<8, 256, 0, stream>>>(b_in, pos, bv_sa, wo_sa, bo_sa,
        bv_ca, wo_ca, bo_ca, bias_in, b_comb);
    transpose_kernel<<<dim3(16, 128), 256, 0, stream>>>(w_in, w_inT, 4096, 512);
    transpose_kernel<<<dim3(64, 16), 256, 0, stream>>>(w_ff1, wff1t, 512, 2048);
    transpose_kernel<<<dim3(16, 64), 256, 0, stream>>>(w_ff2, wff2t, 2048, 512);
    transpose_kernel<<<dim3(16, 16), 256, 0, stream>>>(wo_ca, woT2, 512, 512);
    transpose_kernel<<<dim3(16, 16), 256, 0, stream>>>(wo_sa, woT2 + 512 * 512, 512, 512);
    gather_wh1t<<<1536, 256, 0, stream>>>(wh1, Wh1t);
    gather_wh2t<<<2688, 256, 0, stream>>>(wh2, Wh2t);
    // Wct (z-batched): z=0 -> ca half (k<512), z=1 -> sa half (k>=512)
    gemm64<false, false, false, false><<<dim3(4, 8, 2), 256, 0, stream>>>(
        woT2, nullptr, KBIG, wv2b, nullptr, nullptr, 0, Wct,
        512, 512, 512, 1024, 512 * 512, 512 * 512, 0, 512);

    // ---- main pipeline ----
    // h0 = x @ w_in + (b_in + pos)     (A = f32 x, reg-staged)
    gemm64<false, false, true, false><<<dim3(4, 128), 256, 0, stream>>>(
        x, nullptr, KBIG, w_inT, bias_in, nullptr, 0, h0,
        4096, 4096, 4096, 512, 0, 0, 0, 0);
    // T = ln1(h0)
    ln512_kernel<<<2048, 256, 0, stream>>>(h0, ln1_g, ln1_b, T);
    // h2 = h0 + [h0 | T] @ Wct + b_comb    (fused attention, K=1024)
    gemm64<false, true, false, false><<<dim3(4, 128), 256, 0, stream>>>(
        h0, T, 512, Wct, b_comb, h0, 512, hbuf,
        1024, 512, 1024, 512, 0, 0, 0, 0);
    // T = ln3(h2)
    ln512_kernel<<<2048, 256, 0, stream>>>(hbuf, ln3_g, ln3_b, T);
    // G = gelu(T @ w_ff1 + b_ff1)   [8192, 2048]
    gemm64<true, false, false, false><<<dim3(16, 128), 256, 0, stream>>>(
        T, nullptr, KBIG, wff1t, b_ff1, nullptr, 0, G,
        512, 512, 512, 2048, 0, 0, 0, 0);
    // h3(=h0) = h2 + G @ w_ff2 + b_ff2
    gemm64<false, true, false, false><<<dim3(4, 128), 256, 0, stream>>>(
        G, nullptr, KBIG, wff2t, b_ff2, hbuf, 512, h0,
        2048, 2048, 2048, 512, 0, 0, 0, 0);
    // T = lnout(h3)
    ln512_kernel<<<2048, 256, 0, stream>>>(h0, lnoutg, lnoutb, T);
    // Z = gelu(T @ Wh1 + bh1)   [8192, 768]
    gemm64<true, false, false, false><<<dim3(6, 128), 256, 0, stream>>>(
        T, nullptr, KBIG, Wh1t, bh1, nullptr, 0, Z,
        512, 512, 512, 768, 0, 0, 0, 0);
    // Z2 = per-head LN(Z)
    lnh_kernel<<<6144, 256, 0, stream>>>(Z, lnh_g, lnh_b, Z2);
    // out[:, z*896:(z+1)*896] = Z2[:, z*256:+256] @ wh2[z] + bh2[z]  (f32, z-batched)
    gemm64<false, false, false, true><<<dim3(7, 128, 3), 256, 0, stream>>>(
        Z2, nullptr, KBIG, Wh2t, bh2, nullptr, 0, out,
        256, 768, 256, 2688, 256, 896 * 256, 896, 896);
}

// Round 12
// 434.307 us; speedup vs baseline: 1.0282x; 1.0282x over previous
//
#include <hip/hip_runtime.h>
#include <math.h>

// ---------------------------------------------------------------------------
// RFSQDraftModelWithProjection — f32 in / f32 out, bf16 MFMA compute.
// r12: split-K for the two latency-dominated GEMMs (GEMM1 K=4096 x3,
// attention K=1024 x2) with f32 partials in then-free workspace + fused
// reduce kernels. Counted-vmcnt K-loop retained (harmless).
//
// Algebra: seq_len==1 => attention == out_proj(V(.)):
//   h2 = h0 + [h0 | ln1(h0)] @ Wct + b_comb,  Wct = [wv_ca@wo_ca ; wv_sa@wo_sa]
// ---------------------------------------------------------------------------

typedef unsigned short u16;
typedef __attribute__((ext_vector_type(8))) short bf16x8;
typedef __attribute__((ext_vector_type(4))) float f32x4;
typedef __attribute__((ext_vector_type(8))) unsigned short u16x8;
typedef __attribute__((ext_vector_type(4))) unsigned short u16x4;

__device__ __forceinline__ float bf2f(u16 u){
    union { unsigned int i; float f; } x; x.i = ((unsigned int)u) << 16; return x.f;
}
__device__ __forceinline__ u16 f2bf(float f){
    union { float f; unsigned int i; } x; x.f = f;
    unsigned int r = x.i + 0x7fffu + ((x.i >> 16) & 1u);
    return (u16)(r >> 16);
}
__device__ __forceinline__ float gelu_exact(float v){
    return 0.5f * v * (1.0f + erff(v * 0.7071067811865475f));
}
#define GLOAD16(src, dst) __builtin_amdgcn_global_load_lds( \
    (const __attribute__((address_space(1))) void*)(src),   \
    (__attribute__((address_space(3))) void*)(dst), 16, 0, 0)
#define SCHED0 __builtin_amdgcn_sched_barrier(0)

// ---------------------------------------------------------------------------
// GEMM: C[M,N] = A[M,K] @ B[K,N] (+bias +res, opt GELU).  64x128 tile, BK=32,
// 4 waves (2x2, each 32x64), mfma_f32_16x16x32_bf16, counted-vmcnt dbuf.
// A: AF32=1 -> f32 reg-staged+cvt; else bf16 via global_load_lds.
// A2/ksplit: k0>=ksplit reads A2 (fuses attention K=1024).
// PART=1: split-K — blockIdx.z = k-chunk [z*kch, min(+kch,K)); raw f32
// partial written at Cout + z*czs (no bias/res/gelu).
// PART=0: blockIdx.z = batch with strides azs/bzs/biaszs/czs.
// M%64==0, N%128==0, K%32==0, kch%32==0.
// ---------------------------------------------------------------------------
template<bool GELU, bool RES, bool AF32, bool OUTF32, bool PART>
__global__ __launch_bounds__(256) void gemm64(
    const void* __restrict__ A, const void* __restrict__ A2, int ksplit,
    const u16* __restrict__ Bt, const float* __restrict__ bias,
    const u16* __restrict__ res, int ldr,
    void* __restrict__ Cout, int K, int lda, int ldb, int ldc,
    long azs, long bzs, int biaszs, long czs, int kch)
{
    __shared__ __align__(16) u16 As[2][64 * 32];
    __shared__ __align__(16) u16 Bs[2][128 * 32];
    const int tid = threadIdx.x;
    const int w = tid >> 6, l = tid & 63;
    const int wr = w >> 1, wc = w & 1;
    const int m0 = blockIdx.y * 64, n0 = blockIdx.x * 128;
    const int z = blockIdx.z;
    int kbeg = 0, kend = K;
    if (PART) { kbeg = z * kch; kend = min(kbeg + kch, K); }
    const u16* A16 = (const u16*)A + (PART ? 0 : (size_t)z * azs);
    const float* Af = (const float*)A;
    const u16* BtZ = Bt + (PART ? 0 : (size_t)z * bzs);

    f32x4 acc[2][4];
#pragma unroll
    for (int i = 0; i < 2; ++i)
#pragma unroll
        for (int j = 0; j < 4; ++j) acc[i][j] = (f32x4){0.f, 0.f, 0.f, 0.f};

    float4 pa0, pa1;  // AF32 pending regs
    auto stageB = [&](int buf, int k0) {
#pragma unroll
        for (int j = 0; j < 2; ++j) {
            const u16* gb = BtZ + (size_t)(n0 + (w * 2 + j) * 16 + (l >> 2)) * ldb
                          + k0 + (l & 3) * 8;
            GLOAD16(gb, &Bs[buf][(w * 2 + j) * 512]);
        }
    };
    auto stageA16 = [&](int buf, int k0) {
        const u16* base = (k0 >= ksplit) ? ((const u16*)A2 + (k0 - ksplit)) : (A16 + k0);
        const u16* ga = base + (size_t)(m0 + w * 16 + (l >> 2)) * lda + (l & 3) * 8;
        GLOAD16(ga, &As[buf][w * 512]);
    };
    auto loadA = [&](int k0) {
        const float* g = Af + (size_t)(m0 + (tid >> 2)) * lda + k0 + (tid & 3) * 8;
        pa0 = *(const float4*)g; pa1 = *(const float4*)(g + 4);
    };
    auto writeA = [&](int buf) {
        u16x8 v;
        v[0] = f2bf(pa0.x); v[1] = f2bf(pa0.y); v[2] = f2bf(pa0.z); v[3] = f2bf(pa0.w);
        v[4] = f2bf(pa1.x); v[5] = f2bf(pa1.y); v[6] = f2bf(pa1.z); v[7] = f2bf(pa1.w);
        *(u16x8*)&As[buf][(tid >> 2) * 32 + (tid & 3) * 8] = v;
    };

    const int nt = (kend - kbeg) >> 5;
    // prologue: first tile (A-loads first; writeA's compiler wait = counted)
    if (AF32) loadA(kbeg); else stageA16(0, kbeg);
    stageB(0, kbeg);
    if (AF32) writeA(0);
    int cur = 0;
    for (int t = 0; t < nt; ++t) {
        const bool more = (t + 1) < nt;
        if (more) {
            const int kn = kbeg + ((t + 1) << 5);
            if (AF32) loadA(kn);
            else stageA16(cur ^ 1, kn);
            stageB(cur ^ 1, kn);
        }
        // drain only the PREVIOUS tile's loads; this tile's stay in flight
        if (more) {
            if (AF32) asm volatile("s_waitcnt vmcnt(4) lgkmcnt(0)" ::: "memory");
            else      asm volatile("s_waitcnt vmcnt(3) lgkmcnt(0)" ::: "memory");
        } else {
            asm volatile("s_waitcnt vmcnt(0) lgkmcnt(0)" ::: "memory");
        }
        SCHED0;
        __builtin_amdgcn_s_barrier();
        SCHED0;
        bf16x8 a[2], b[4];
#pragma unroll
        for (int i = 0; i < 2; ++i)
            a[i] = *(const bf16x8*)&As[cur][(wr * 32 + i * 16 + (l & 15)) * 32 + (l >> 4) * 8];
#pragma unroll
        for (int j = 0; j < 4; ++j)
            b[j] = *(const bf16x8*)&Bs[cur][(wc * 64 + j * 16 + (l & 15)) * 32 + (l >> 4) * 8];
#pragma unroll
        for (int i = 0; i < 2; ++i)
#pragma unroll
            for (int j = 0; j < 4; ++j)
                acc[i][j] = __builtin_amdgcn_mfma_f32_16x16x32_bf16(a[i], b[j], acc[i][j], 0, 0, 0);
        if (AF32 && more) writeA(cur ^ 1);
        asm volatile("" ::: "memory");
        SCHED0;
        __builtin_amdgcn_s_barrier();
        SCHED0;
        cur ^= 1;
    }

    // epilogue: C/D layout col = l&15, row = (l>>4)*4 + r  [m89/m91]
    float* cF = (float*)Cout + (size_t)z * czs;
    u16*   cH = (u16*)Cout + (size_t)z * czs;
    const float* biasZ = (!PART && bias) ? bias + (size_t)z * biaszs : nullptr;
#pragma unroll
    for (int i = 0; i < 2; ++i) {
#pragma unroll
        for (int j = 0; j < 4; ++j) {
            const int col = n0 + wc * 64 + j * 16 + (l & 15);
            const int rowb = m0 + wr * 32 + i * 16 + (l >> 4) * 4;
#pragma unroll
            for (int r = 0; r < 4; ++r) {
                const int row = rowb + r;
                float v = acc[i][j][r];
                if (PART) {
                    cF[(size_t)row * ldc + col] = v;
                } else {
                    if (biasZ) v += biasZ[col];
                    if (RES) v += bf2f(res[(size_t)row * ldr + col]);
                    if (GELU) v = gelu_exact(v);
                    if (OUTF32) cF[(size_t)row * ldc + col] = v;
                    else        cH[(size_t)row * ldc + col] = f2bf(v);
                }
            }
        }
    }
}

// split-K reduce over [8192,512]: out = bf16(sum_p part[p] + bias (+res))
template<int NP>
__global__ __launch_bounds__(256) void reduceK(
    const float* __restrict__ part, long pzs, const float* __restrict__ bias,
    const u16* __restrict__ res, u16* __restrict__ out)
{
    const int idx = (blockIdx.x * 256 + threadIdx.x) * 4;
    const int col = idx & 511;
    float4 s = *(const float4*)(part + idx);
#pragma unroll
    for (int p = 1; p < NP; ++p) {
        const float4 v = *(const float4*)(part + (size_t)p * pzs + idx);
        s.x += v.x; s.y += v.y; s.z += v.z; s.w += v.w;
    }
    const float4 b = *(const float4*)(bias + col);
    s.x += b.x; s.y += b.y; s.z += b.z; s.w += b.w;
    if (res) {
        const u16x4 r = *(const u16x4*)(res + idx);
        s.x += bf2f(r[0]); s.y += bf2f(r[1]); s.z += bf2f(r[2]); s.w += bf2f(r[3]);
    }
    u16x4 o;
    o[0] = f2bf(s.x); o[1] = f2bf(s.y); o[2] = f2bf(s.z); o[3] = f2bf(s.w);
    *(u16x4*)(out + idx) = o;
}

// f32 -> bf16 bulk convert, 8 elems/thread
__global__ __launch_bounds__(256) void cvt_f32_bf16(
    const float* __restrict__ in, u16* __restrict__ out, int n8)
{
    const int i = blockIdx.x * 256 + threadIdx.x;
    if (i >= n8) return;
    const float4* p = (const float4*)in + (size_t)i * 2;
    const float4 a = p[0], b = p[1];
    u16x8 v;
    v[0] = f2bf(a.x); v[1] = f2bf(a.y); v[2] = f2bf(a.z); v[3] = f2bf(a.w);
    v[4] = f2bf(b.x); v[5] = f2bf(b.y); v[6] = f2bf(b.z); v[7] = f2bf(b.w);
    *(u16x8*)(out + (size_t)i * 8) = v;
}

// LayerNorm over 512 cols (bf16 in/out, f32 g/b), one wave per row
__global__ __launch_bounds__(256) void ln512_kernel(
    const u16* __restrict__ in, const float* __restrict__ g,
    const float* __restrict__ b, u16* __restrict__ out)
{
    const int wid = threadIdx.x >> 6, l = threadIdx.x & 63;
    const size_t row = (size_t)blockIdx.x * 4 + wid;
    u16x8 v = *(const u16x8*)(in + row * 512 + l * 8);
    float f[8], s = 0.f, q = 0.f;
#pragma unroll
    for (int j = 0; j < 8; ++j) { f[j] = bf2f(v[j]); s += f[j]; q += f[j] * f[j]; }
#pragma unroll
    for (int o = 32; o > 0; o >>= 1) { s += __shfl_xor(s, o); q += __shfl_xor(q, o); }
    const float mean = s * (1.f / 512.f);
    const float var = q * (1.f / 512.f) - mean * mean;
    const float rstd = rsqrtf(var + 1e-5f);
    u16x8 ov;
#pragma unroll
    for (int j = 0; j < 8; ++j) {
        const int c = l * 8 + j;
        ov[j] = f2bf((f[j] - mean) * rstd * g[c] + b[c]);
    }
    *(u16x8*)(out + row * 512 + l * 8) = ov;
}

// per-head LN over 256 (rows are [8192,768], heads of 256), wave per (row,head)
__global__ __launch_bounds__(256) void lnh_kernel(
    const u16* __restrict__ in, const float* __restrict__ g,
    const float* __restrict__ b, u16* __restrict__ out)
{
    const int wid = threadIdx.x >> 6, l = threadIdx.x & 63;
    const int unit = blockIdx.x * 4 + wid;        // unit = h*8192 + row
    const int h = unit >> 13, row = unit & 8191;
    const size_t base = (size_t)row * 768 + h * 256 + l * 4;
    u16x4 v = *(const u16x4*)(in + base);
    float f[4], s = 0.f, q = 0.f;
#pragma unroll
    for (int j = 0; j < 4; ++j) { f[j] = bf2f(v[j]); s += f[j]; q += f[j] * f[j]; }
#pragma unroll
    for (int o = 32; o > 0; o >>= 1) { s += __shfl_xor(s, o); q += __shfl_xor(q, o); }
    const float mean = s * (1.f / 256.f);
    const float var = q * (1.f / 256.f) - mean * mean;
    const float rstd = rsqrtf(var + 1e-5f);
    u16x4 ov;
#pragma unroll
    for (int j = 0; j < 4; ++j) {
        const int c = h * 256 + l * 4 + j;
        ov[j] = f2bf((f[j] - mean) * rstd * g[c] + b[c]);
    }
    *(u16x4*)(out + base) = ov;
}

// out[N,K](bf16) = in[K,N](f32)^T, dims % 32 == 0, block = 256 (32x8)
__global__ __launch_bounds__(256) void transpose_kernel(
    const float* __restrict__ in, u16* __restrict__ out, int K, int N)
{
    __shared__ u16 t[32][33];
    const int n0 = blockIdx.x * 32, k0 = blockIdx.y * 32;
    const int tx = threadIdx.x & 31, ty = threadIdx.x >> 5;
#pragma unroll
    for (int i = 0; i < 32; i += 8)
        t[ty + i][tx] = f2bf(in[(size_t)(k0 + ty + i) * N + (n0 + tx)]);
    __syncthreads();
#pragma unroll
    for (int i = 0; i < 32; i += 8)
        out[(size_t)(n0 + ty + i) * K + (k0 + tx)] = t[tx][ty + i];
}

// Wh1t[768][512](bf16): Wh1t[h*256+k][d] = wh1[h][d][k]
__global__ void gather_wh1t(const float* __restrict__ wh1, u16* __restrict__ out)
{
    const int idx = blockIdx.x * 256 + threadIdx.x;
    if (idx >= 768 * 512) return;
    const int d = idx & 511, j = idx >> 9;
    const int h = j >> 8, kk = j & 255;
    out[idx] = f2bf(wh1[((size_t)(h * 512 + d)) * 256 + kk]);
}

// Wh2t[3][896][256](bf16): Wh2t[h][o][k] = wh2[h][k][o]
__global__ void gather_wh2t(const float* __restrict__ wh2, u16* __restrict__ out)
{
    const int idx = blockIdx.x * 256 + threadIdx.x;
    if (idx >= 3 * 896 * 256) return;
    const int kk = idx & 255, t = idx >> 8;
    const int h = t / 896, o = t - h * 896;
    out[idx] = f2bf(wh2[((size_t)(h * 256 + kk)) * 896 + o]);
}

// parallel bias prep: 8 blocks; block b covers i in [b*64, b*64+64).
__global__ __launch_bounds__(256) void prep_bias_kernel(
    const float* __restrict__ b_in, const float* __restrict__ pos,
    const float* __restrict__ bv_sa, const float* __restrict__ wo_sa,
    const float* __restrict__ bo_sa,
    const float* __restrict__ bv_ca, const float* __restrict__ wo_ca,
    const float* __restrict__ bo_ca,
    float* __restrict__ bias_in, float* __restrict__ b_comb)
{
    __shared__ float psa[4][64], pca[4][64];
    const int ii = threadIdx.x & 63, kg = threadIdx.x >> 6;
    const int i = blockIdx.x * 64 + ii;
    float sa = 0.f, ca = 0.f;
    for (int k = kg; k < 512; k += 4) {
        sa += bv_sa[k] * wo_sa[(size_t)k * 512 + i];
        ca += bv_ca[k] * wo_ca[(size_t)k * 512 + i];
    }
    psa[kg][ii] = sa; pca[kg][ii] = ca;
    __syncthreads();
    if (kg == 0) {
        bias_in[i] = b_in[i] + pos[i];
        b_comb[i] = psa[0][ii] + psa[1][ii] + psa[2][ii] + psa[3][ii]
                  + pca[0][ii] + pca[1][ii] + pca[2][ii] + pca[3][ii]
                  + bo_sa[i] + bo_ca[i];
    }
}

extern "C" void kernel_launch(void* const* d_in, const int* in_sizes, int n_in,
                              void* d_out, int out_size, void* d_ws, size_t ws_size,
                              hipStream_t stream)
{
    const float* x      = (const float*)d_in[0];
    const float* w_in   = (const float*)d_in[1];
    const float* b_in   = (const float*)d_in[2];
    const float* pos    = (const float*)d_in[3];
    const float* ln1_g  = (const float*)d_in[4];
    const float* ln1_b  = (const float*)d_in[5];
    const float* wv_sa  = (const float*)d_in[6];
    const float* bv_sa  = (const float*)d_in[7];
    const float* wo_sa  = (const float*)d_in[8];
    const float* bo_sa  = (const float*)d_in[9];
    const float* wv_ca  = (const float*)d_in[12];
    const float* bv_ca  = (const float*)d_in[13];
    const float* wo_ca  = (const float*)d_in[14];
    const float* bo_ca  = (const float*)d_in[15];
    const float* ln3_g  = (const float*)d_in[16];
    const float* ln3_b  = (const float*)d_in[17];
    const float* w_ff1  = (const float*)d_in[18];
    const float* b_ff1  = (const float*)d_in[19];
    const float* w_ff2  = (const float*)d_in[20];
    const float* b_ff2  = (const float*)d_in[21];
    const float* lnoutg = (const float*)d_in[22];
    const float* lnoutb = (const float*)d_in[23];
    const float* wh1    = (const float*)d_in[24];
    const float* bh1    = (const float*)d_in[25];
    const float* lnh_g  = (const float*)d_in[26];
    const float* lnh_b  = (const float*)d_in[27];
    const float* wh2    = (const float*)d_in[28];
    const float* bh2    = (const float*)d_in[29];
    float* out = (float*)d_out;
    const int KBIG = 0x7fffffff;

    // ---- workspace layout (~70 MB, rewritten fully every call) ----
    char* wsp = (char*)d_ws;
    size_t off = 0;
    auto ALLOC = [&](size_t n) { char* r = wsp + off; off = (off + n + 255) & ~(size_t)255; return r; };
    u16* w_inT  = (u16*)ALLOC(512UL * 4096 * 2);
    u16* wff1t  = (u16*)ALLOC(2048UL * 512 * 2);
    u16* wff2t  = (u16*)ALLOC(512UL * 2048 * 2);
    u16* woT2   = (u16*)ALLOC(2UL * 512 * 512 * 2);  // [0]=woTca, [1]=woTsa
    u16* wv2b   = (u16*)ALLOC(2UL * 512 * 512 * 2);  // [0]=wv_ca, [1]=wv_sa
    u16* Wct    = (u16*)ALLOC(512UL * 1024 * 2);     // [n][k] k<512: ca, k>=512: sa
    u16* Wh1t   = (u16*)ALLOC(768UL * 512 * 2);
    u16* Wh2t   = (u16*)ALLOC(3UL * 896 * 256 * 2);
    float* bias_in = (float*)ALLOC(512 * 4);
    float* b_comb  = (float*)ALLOC(512 * 4);
    u16* h0   = (u16*)ALLOC(8192UL * 512 * 2);   // h0, later reused as h3
    u16* T    = (u16*)ALLOC(8192UL * 512 * 2);   // ln1 / ln3 / lnout output
    u16* hbuf = (u16*)ALLOC(8192UL * 512 * 2);   // h2
    u16* G    = (u16*)ALLOC(8192UL * 2048 * 2);  // FF intermediate; Z/Z2 alias
    u16* Z  = G;
    u16* Z2 = (u16*)((char*)G + 8192UL * 768 * 2);
    // split-K partial regions (alias buffers that are FREE at that stage):
    float* part1 = (float*)T;   // GEMM1: spans T+hbuf+G (3 x 16.78 MB) — all free
    float* part2 = (float*)G;   // attention: 2 x 16.78 MB in G — free
    const long PZS = 8192L * 512;

    // ---- weight prep ----
    cvt_f32_bf16<<<128, 256, 0, stream>>>(wv_ca, wv2b, 512 * 512 / 8);
    cvt_f32_bf16<<<128, 256, 0, stream>>>(wv_sa, wv2b + 512 * 512, 512 * 512 / 8);
    prep_bias_kernel<<<8, 256, 0, stream>>>(b_in, pos, bv_sa, wo_sa, bo_sa,
        bv_ca, wo_ca, bo_ca, bias_in, b_comb);
    transpose_kernel<<<dim3(16, 128), 256, 0, stream>>>(w_in, w_inT, 4096, 512);
    transpose_kernel<<<dim3(64, 16), 256, 0, stream>>>(w_ff1, wff1t, 512, 2048);
    transpose_kernel<<<dim3(16, 64), 256, 0, stream>>>(w_ff2, wff2t, 2048, 512);
    transpose_kernel<<<dim3(16, 16), 256, 0, stream>>>(wo_ca, woT2, 512, 512);
    transpose_kernel<<<dim3(16, 16), 256, 0, stream>>>(wo_sa, woT2 + 512 * 512, 512, 512);
    gather_wh1t<<<1536, 256, 0, stream>>>(wh1, Wh1t);
    gather_wh2t<<<2688, 256, 0, stream>>>(wh2, Wh2t);
    // Wct (z-batched): z=0 -> ca half (k<512), z=1 -> sa half (k>=512)
    gemm64<false, false, false, false, false><<<dim3(4, 8, 2), 256, 0, stream>>>(
        woT2, nullptr, KBIG, wv2b, nullptr, nullptr, 0, Wct,
        512, 512, 512, 1024, 512 * 512, 512 * 512, 0, 512, 0);

    // ---- main pipeline ----
    // GEMM1 split-K x3 (chunks 1376/1376/1344): partials, then reduce+bias
    gemm64<false, false, true, false, true><<<dim3(4, 128, 3), 256, 0, stream>>>(
        x, nullptr, KBIG, w_inT, nullptr, nullptr, 0, part1,
        4096, 4096, 4096, 512, 0, 0, 0, PZS, 1376);
    reduceK<3><<<4096, 256, 0, stream>>>(part1, PZS, bias_in, nullptr, h0);
    // T = ln1(h0)   (T overlaps part1 chunk0 — partials already consumed)
    ln512_kernel<<<2048, 256, 0, stream>>>(h0, ln1_g, ln1_b, T);
    // attention split-K x2: [h0 | T] @ Wct -> partials in G; reduce fuses
    // +b_comb +h0 residual -> h2 (hbuf)
    gemm64<false, false, false, false, true><<<dim3(4, 128, 2), 256, 0, stream>>>(
        h0, T, 512, Wct, nullptr, nullptr, 0, part2,
        1024, 512, 1024, 512, 0, 0, 0, PZS, 512);
    reduceK<2><<<4096, 256, 0, stream>>>(part2, PZS, b_comb, h0, hbuf);
    // T = ln3(h2)
    ln512_kernel<<<2048, 256, 0, stream>>>(hbuf, ln3_g, ln3_b, T);
    // G = gelu(T @ w_ff1 + b_ff1)   [8192, 2048]
    gemm64<true, false, false, false, false><<<dim3(16, 128), 256, 0, stream>>>(
        T, nullptr, KBIG, wff1t, b_ff1, nullptr, 0, G,
        512, 512, 512, 2048, 0, 0, 0, 0, 0);
    // h3(=h0) = h2 + G @ w_ff2 + b_ff2
    gemm64<false, true, false, false, false><<<dim3(4, 128), 256, 0, stream>>>(
        G, nullptr, KBIG, wff2t, b_ff2, hbuf, 512, h0,
        2048, 2048, 2048, 512, 0, 0, 0, 0, 0);
    // T = lnout(h3)
    ln512_kernel<<<2048, 256, 0, stream>>>(h0, lnoutg, lnoutb, T);
    // Z = gelu(T @ Wh1 + bh1)   [8192, 768]
    gemm64<true, false, false, false, false><<<dim3(6, 128), 256, 0, stream>>>(
        T, nullptr, KBIG, Wh1t, bh1, nullptr, 0, Z,
        512, 512, 512, 768, 0, 0, 0, 0, 0);
    // Z2 = per-head LN(Z)
    lnh_kernel<<<6144, 256, 0, stream>>>(Z, lnh_g, lnh_b, Z2);
    // out[:, z*896:(z+1)*896] = Z2[:, z*256:+256] @ wh2[z] + bh2[z]  (f32, z-batched)
    gemm64<false, false, false, true, false><<<dim3(7, 128, 3), 256, 0, stream>>>(
        Z2, nullptr, KBIG, Wh2t, bh2, nullptr, 0, out,
        256, 768, 256, 2688, 256, 896 * 256, 896, 896, 0);
}

// Round 13
// 402.751 us; speedup vs baseline: 1.1088x; 1.0784x over previous
//
#include <hip/hip_runtime.h>
#include <math.h>

// ---------------------------------------------------------------------------
// RFSQDraftModelWithProjection — f32 in / f32 out, bf16 MFMA compute.
// r13: (1) m-tile on blockIdx.x (gridDim.x % 8 == 0) so all n/z blocks of an
// m-tile share one XCD's L2 (A-panel fetched once from HBM); (2) AF32 path
// depth-2 register prefetch (full-step latency cover) with counted vmcnt and
// explicit lgkmcnt(0) before the publishing barrier.
//
// Algebra: seq_len==1 => attention == out_proj(V(.)):
//   h2 = h0 + [h0 | ln1(h0)] @ Wct + b_comb,  Wct = [wv_ca@wo_ca ; wv_sa@wo_sa]
// ---------------------------------------------------------------------------

typedef unsigned short u16;
typedef __attribute__((ext_vector_type(8))) short bf16x8;
typedef __attribute__((ext_vector_type(4))) float f32x4;
typedef __attribute__((ext_vector_type(8))) unsigned short u16x8;
typedef __attribute__((ext_vector_type(4))) unsigned short u16x4;

__device__ __forceinline__ float bf2f(u16 u){
    union { unsigned int i; float f; } x; x.i = ((unsigned int)u) << 16; return x.f;
}
__device__ __forceinline__ u16 f2bf(float f){
    union { float f; unsigned int i; } x; x.f = f;
    unsigned int r = x.i + 0x7fffu + ((x.i >> 16) & 1u);
    return (u16)(r >> 16);
}
__device__ __forceinline__ float gelu_exact(float v){
    return 0.5f * v * (1.0f + erff(v * 0.7071067811865475f));
}
#define GLOAD16(src, dst) __builtin_amdgcn_global_load_lds( \
    (const __attribute__((address_space(1))) void*)(src),   \
    (__attribute__((address_space(3))) void*)(dst), 16, 0, 0)
#define SCHED0 __builtin_amdgcn_sched_barrier(0)

// ---------------------------------------------------------------------------
// GEMM: C[M,N] = A[M,K] @ B[K,N] (+bias +res, opt GELU).  64x128 tile, BK=32,
// 4 waves (2x2, each 32x64), mfma_f32_16x16x32_bf16.
// blockIdx.x = m-tile (XCD L2 A-sharing), blockIdx.y = n-tile.
// A: AF32=1 -> f32 depth-2 reg prefetch + cvt; else bf16 via global_load_lds
// (counted-vmcnt double buffer).
// A2/ksplit: k0>=ksplit reads A2 (fuses attention K=1024).
// PART=1: blockIdx.z = k-chunk; raw f32 partial at Cout + z*czs.
// PART=0: blockIdx.z = batch with strides azs/bzs/biaszs/czs.
// M%64==0, N%128==0, K%32==0, kch%32==0.
// ---------------------------------------------------------------------------
template<bool GELU, bool RES, bool AF32, bool OUTF32, bool PART>
__global__ __launch_bounds__(256) void gemm64(
    const void* __restrict__ A, const void* __restrict__ A2, int ksplit,
    const u16* __restrict__ Bt, const float* __restrict__ bias,
    const u16* __restrict__ res, int ldr,
    void* __restrict__ Cout, int K, int lda, int ldb, int ldc,
    long azs, long bzs, int biaszs, long czs, int kch)
{
    __shared__ __align__(16) u16 As[2][64 * 32];
    __shared__ __align__(16) u16 Bs[2][128 * 32];
    const int tid = threadIdx.x;
    const int w = tid >> 6, l = tid & 63;
    const int wr = w >> 1, wc = w & 1;
    const int m0 = blockIdx.x * 64, n0 = blockIdx.y * 128;
    const int z = blockIdx.z;
    int kbeg = 0, kend = K;
    if (PART) { kbeg = z * kch; kend = min(kbeg + kch, K); }
    const u16* A16 = (const u16*)A + (PART ? 0 : (size_t)z * azs);
    const float* Af = (const float*)A;
    const u16* BtZ = Bt + (PART ? 0 : (size_t)z * bzs);

    f32x4 acc[2][4];
#pragma unroll
    for (int i = 0; i < 2; ++i)
#pragma unroll
        for (int j = 0; j < 4; ++j) acc[i][j] = (f32x4){0.f, 0.f, 0.f, 0.f};

    auto stageB = [&](int buf, int k0) {
#pragma unroll
        for (int j = 0; j < 2; ++j) {
            const u16* gb = BtZ + (size_t)(n0 + (w * 2 + j) * 16 + (l >> 2)) * ldb
                          + k0 + (l & 3) * 8;
            GLOAD16(gb, &Bs[buf][(w * 2 + j) * 512]);
        }
    };
    auto stageA16 = [&](int buf, int k0) {
        const u16* base = (k0 >= ksplit) ? ((const u16*)A2 + (k0 - ksplit)) : (A16 + k0);
        const u16* ga = base + (size_t)(m0 + w * 16 + (l >> 2)) * lda + (l & 3) * 8;
        GLOAD16(ga, &As[buf][w * 512]);
    };
    auto loadA = [&](int k0, float4& p0, float4& p1) {
        const float* g = Af + (size_t)(m0 + (tid >> 2)) * lda + k0 + (tid & 3) * 8;
        p0 = *(const float4*)g; p1 = *(const float4*)(g + 4);
    };
    auto writeA = [&](const float4& p0, const float4& p1, int buf) {
        u16x8 v;
        v[0] = f2bf(p0.x); v[1] = f2bf(p0.y); v[2] = f2bf(p0.z); v[3] = f2bf(p0.w);
        v[4] = f2bf(p1.x); v[5] = f2bf(p1.y); v[6] = f2bf(p1.z); v[7] = f2bf(p1.w);
        *(u16x8*)&As[buf][(tid >> 2) * 32 + (tid & 3) * 8] = v;
    };
    int cur = 0;
    auto compute = [&]() {
        bf16x8 a[2], b[4];
#pragma unroll
        for (int i = 0; i < 2; ++i)
            a[i] = *(const bf16x8*)&As[cur][(wr * 32 + i * 16 + (l & 15)) * 32 + (l >> 4) * 8];
#pragma unroll
        for (int j = 0; j < 4; ++j)
            b[j] = *(const bf16x8*)&Bs[cur][(wc * 64 + j * 16 + (l & 15)) * 32 + (l >> 4) * 8];
#pragma unroll
        for (int i = 0; i < 2; ++i)
#pragma unroll
            for (int j = 0; j < 4; ++j)
                acc[i][j] = __builtin_amdgcn_mfma_f32_16x16x32_bf16(a[i], b[j], acc[i][j], 0, 0, 0);
    };

    const int nt = (kend - kbeg) >> 5;
    if (AF32) {
        // depth-2 register pipeline: during step t, LDS-write tile t+1 (regs
        // loaded in step t-1) and load tile t+2 into the other reg set.
        float4 a0, a1, b0, b1;
        loadA(kbeg, a0, a1);
        stageB(0, kbeg);
        if (nt > 1) loadA(kbeg + 32, b0, b1);
        if (nt > 1) asm volatile("s_waitcnt vmcnt(4)" ::: "memory");
        else        asm volatile("s_waitcnt vmcnt(2)" ::: "memory");
        writeA(a0, a1, 0);
        asm volatile("s_waitcnt lgkmcnt(0)" ::: "memory");
        auto stepA = [&](int t, float4& w0, float4& w1, float4& l0, float4& l1) {
            const bool ldA = (t + 2) < nt;
            const bool stB = (t + 1) < nt;
            if (ldA) loadA(kbeg + ((t + 2) << 5), l0, l1);
            if (stB) stageB(cur ^ 1, kbeg + ((t + 1) << 5));
            if (ldA)      asm volatile("s_waitcnt vmcnt(4)" ::: "memory");
            else if (stB) asm volatile("s_waitcnt vmcnt(2)" ::: "memory");
            else          asm volatile("s_waitcnt vmcnt(0)" ::: "memory");
            SCHED0;
            __builtin_amdgcn_s_barrier();
            SCHED0;
            compute();
            if (stB) writeA(w0, w1, cur ^ 1);
            asm volatile("s_waitcnt lgkmcnt(0)" ::: "memory");
            SCHED0;
            __builtin_amdgcn_s_barrier();
            SCHED0;
            cur ^= 1;
        };
        int t = 0;
        while (t + 2 <= nt) {
            stepA(t,     b0, b1, a0, a1);
            stepA(t + 1, a0, a1, b0, b1);
            t += 2;
        }
        if (t < nt) stepA(t, b0, b1, a0, a1);
    } else {
        stageA16(0, kbeg);
        stageB(0, kbeg);
        for (int t = 0; t < nt; ++t) {
            const bool more = (t + 1) < nt;
            if (more) {
                const int kn = kbeg + ((t + 1) << 5);
                stageA16(cur ^ 1, kn);
                stageB(cur ^ 1, kn);
            }
            if (more) asm volatile("s_waitcnt vmcnt(3)" ::: "memory");
            else      asm volatile("s_waitcnt vmcnt(0)" ::: "memory");
            SCHED0;
            __builtin_amdgcn_s_barrier();
            SCHED0;
            compute();
            asm volatile("" ::: "memory");
            SCHED0;
            __builtin_amdgcn_s_barrier();
            SCHED0;
            cur ^= 1;
        }
    }

    // epilogue: C/D layout col = l&15, row = (l>>4)*4 + r  [m89/m91]
    float* cF = (float*)Cout + (size_t)z * czs;
    u16*   cH = (u16*)Cout + (size_t)z * czs;
    const float* biasZ = (!PART && bias) ? bias + (size_t)z * biaszs : nullptr;
#pragma unroll
    for (int i = 0; i < 2; ++i) {
#pragma unroll
        for (int j = 0; j < 4; ++j) {
            const int col = n0 + wc * 64 + j * 16 + (l & 15);
            const int rowb = m0 + wr * 32 + i * 16 + (l >> 4) * 4;
#pragma unroll
            for (int r = 0; r < 4; ++r) {
                const int row = rowb + r;
                float v = acc[i][j][r];
                if (PART) {
                    cF[(size_t)row * ldc + col] = v;
                } else {
                    if (biasZ) v += biasZ[col];
                    if (RES) v += bf2f(res[(size_t)row * ldr + col]);
                    if (GELU) v = gelu_exact(v);
                    if (OUTF32) cF[(size_t)row * ldc + col] = v;
                    else        cH[(size_t)row * ldc + col] = f2bf(v);
                }
            }
        }
    }
}

// split-K reduce over [8192,512]: out = bf16(sum_p part[p] + bias (+res))
template<int NP>
__global__ __launch_bounds__(256) void reduceK(
    const float* __restrict__ part, long pzs, const float* __restrict__ bias,
    const u16* __restrict__ res, u16* __restrict__ out)
{
    const int idx = (blockIdx.x * 256 + threadIdx.x) * 4;
    const int col = idx & 511;
    float4 s = *(const float4*)(part + idx);
#pragma unroll
    for (int p = 1; p < NP; ++p) {
        const float4 v = *(const float4*)(part + (size_t)p * pzs + idx);
        s.x += v.x; s.y += v.y; s.z += v.z; s.w += v.w;
    }
    const float4 b = *(const float4*)(bias + col);
    s.x += b.x; s.y += b.y; s.z += b.z; s.w += b.w;
    if (res) {
        const u16x4 r = *(const u16x4*)(res + idx);
        s.x += bf2f(r[0]); s.y += bf2f(r[1]); s.z += bf2f(r[2]); s.w += bf2f(r[3]);
    }
    u16x4 o;
    o[0] = f2bf(s.x); o[1] = f2bf(s.y); o[2] = f2bf(s.z); o[3] = f2bf(s.w);
    *(u16x4*)(out + idx) = o;
}

// f32 -> bf16 bulk convert, 8 elems/thread
__global__ __launch_bounds__(256) void cvt_f32_bf16(
    const float* __restrict__ in, u16* __restrict__ out, int n8)
{
    const int i = blockIdx.x * 256 + threadIdx.x;
    if (i >= n8) return;
    const float4* p = (const float4*)in + (size_t)i * 2;
    const float4 a = p[0], b = p[1];
    u16x8 v;
    v[0] = f2bf(a.x); v[1] = f2bf(a.y); v[2] = f2bf(a.z); v[3] = f2bf(a.w);
    v[4] = f2bf(b.x); v[5] = f2bf(b.y); v[6] = f2bf(b.z); v[7] = f2bf(b.w);
    *(u16x8*)(out + (size_t)i * 8) = v;
}

// LayerNorm over 512 cols (bf16 in/out, f32 g/b), one wave per row
__global__ __launch_bounds__(256) void ln512_kernel(
    const u16* __restrict__ in, const float* __restrict__ g,
    const float* __restrict__ b, u16* __restrict__ out)
{
    const int wid = threadIdx.x >> 6, l = threadIdx.x & 63;
    const size_t row = (size_t)blockIdx.x * 4 + wid;
    u16x8 v = *(const u16x8*)(in + row * 512 + l * 8);
    float f[8], s = 0.f, q = 0.f;
#pragma unroll
    for (int j = 0; j < 8; ++j) { f[j] = bf2f(v[j]); s += f[j]; q += f[j] * f[j]; }
#pragma unroll
    for (int o = 32; o > 0; o >>= 1) { s += __shfl_xor(s, o); q += __shfl_xor(q, o); }
    const float mean = s * (1.f / 512.f);
    const float var = q * (1.f / 512.f) - mean * mean;
    const float rstd = rsqrtf(var + 1e-5f);
    u16x8 ov;
#pragma unroll
    for (int j = 0; j < 8; ++j) {
        const int c = l * 8 + j;
        ov[j] = f2bf((f[j] - mean) * rstd * g[c] + b[c]);
    }
    *(u16x8*)(out + row * 512 + l * 8) = ov;
}

// per-head LN over 256 (rows are [8192,768], heads of 256), wave per (row,head)
__global__ __launch_bounds__(256) void lnh_kernel(
    const u16* __restrict__ in, const float* __restrict__ g,
    const float* __restrict__ b, u16* __restrict__ out)
{
    const int wid = threadIdx.x >> 6, l = threadIdx.x & 63;
    const int unit = blockIdx.x * 4 + wid;        // unit = h*8192 + row
    const int h = unit >> 13, row = unit & 8191;
    const size_t base = (size_t)row * 768 + h * 256 + l * 4;
    u16x4 v = *(const u16x4*)(in + base);
    float f[4], s = 0.f, q = 0.f;
#pragma unroll
    for (int j = 0; j < 4; ++j) { f[j] = bf2f(v[j]); s += f[j]; q += f[j] * f[j]; }
#pragma unroll
    for (int o = 32; o > 0; o >>= 1) { s += __shfl_xor(s, o); q += __shfl_xor(q, o); }
    const float mean = s * (1.f / 256.f);
    const float var = q * (1.f / 256.f) - mean * mean;
    const float rstd = rsqrtf(var + 1e-5f);
    u16x4 ov;
#pragma unroll
    for (int j = 0; j < 4; ++j) {
        const int c = h * 256 + l * 4 + j;
        ov[j] = f2bf((f[j] - mean) * rstd * g[c] + b[c]);
    }
    *(u16x4*)(out + base) = ov;
}

// out[N,K](bf16) = in[K,N](f32)^T, dims % 32 == 0, block = 256 (32x8)
__global__ __launch_bounds__(256) void transpose_kernel(
    const float* __restrict__ in, u16* __restrict__ out, int K, int N)
{
    __shared__ u16 t[32][33];
    const int n0 = blockIdx.x * 32, k0 = blockIdx.y * 32;
    const int tx = threadIdx.x & 31, ty = threadIdx.x >> 5;
#pragma unroll
    for (int i = 0; i < 32; i += 8)
        t[ty + i][tx] = f2bf(in[(size_t)(k0 + ty + i) * N + (n0 + tx)]);
    __syncthreads();
#pragma unroll
    for (int i = 0; i < 32; i += 8)
        out[(size_t)(n0 + ty + i) * K + (k0 + tx)] = t[tx][ty + i];
}

// Wh1t[768][512](bf16): Wh1t[h*256+k][d] = wh1[h][d][k]
__global__ void gather_wh1t(const float* __restrict__ wh1, u16* __restrict__ out)
{
    const int idx = blockIdx.x * 256 + threadIdx.x;
    if (idx >= 768 * 512) return;
    const int d = idx & 511, j = idx >> 9;
    const int h = j >> 8, kk = j & 255;
    out[idx] = f2bf(wh1[((size_t)(h * 512 + d)) * 256 + kk]);
}

// Wh2t[3][896][256](bf16): Wh2t[h][o][k] = wh2[h][k][o]
__global__ void gather_wh2t(const float* __restrict__ wh2, u16* __restrict__ out)
{
    const int idx = blockIdx.x * 256 + threadIdx.x;
    if (idx >= 3 * 896 * 256) return;
    const int kk = idx & 255, t = idx >> 8;
    const int h = t / 896, o = t - h * 896;
    out[idx] = f2bf(wh2[((size_t)(h * 256 + kk)) * 896 + o]);
}

// parallel bias prep: 8 blocks; block b covers i in [b*64, b*64+64).
__global__ __launch_bounds__(256) void prep_bias_kernel(
    const float* __restrict__ b_in, const float* __restrict__ pos,
    const float* __restrict__ bv_sa, const float* __restrict__ wo_sa,
    const float* __restrict__ bo_sa,
    const float* __restrict__ bv_ca, const float* __restrict__ wo_ca,
    const float* __restrict__ bo_ca,
    float* __restrict__ bias_in, float* __restrict__ b_comb)
{
    __shared__ float psa[4][64], pca[4][64];
    const int ii = threadIdx.x & 63, kg = threadIdx.x >> 6;
    const int i = blockIdx.x * 64 + ii;
    float sa = 0.f, ca = 0.f;
    for (int k = kg; k < 512; k += 4) {
        sa += bv_sa[k] * wo_sa[(size_t)k * 512 + i];
        ca += bv_ca[k] * wo_ca[(size_t)k * 512 + i];
    }
    psa[kg][ii] = sa; pca[kg][ii] = ca;
    __syncthreads();
    if (kg == 0) {
        bias_in[i] = b_in[i] + pos[i];
        b_comb[i] = psa[0][ii] + psa[1][ii] + psa[2][ii] + psa[3][ii]
                  + pca[0][ii] + pca[1][ii] + pca[2][ii] + pca[3][ii]
                  + bo_sa[i] + bo_ca[i];
    }
}

extern "C" void kernel_launch(void* const* d_in, const int* in_sizes, int n_in,
                              void* d_out, int out_size, void* d_ws, size_t ws_size,
                              hipStream_t stream)
{
    const float* x      = (const float*)d_in[0];
    const float* w_in   = (const float*)d_in[1];
    const float* b_in   = (const float*)d_in[2];
    const float* pos    = (const float*)d_in[3];
    const float* ln1_g  = (const float*)d_in[4];
    const float* ln1_b  = (const float*)d_in[5];
    const float* wv_sa  = (const float*)d_in[6];
    const float* bv_sa  = (const float*)d_in[7];
    const float* wo_sa  = (const float*)d_in[8];
    const float* bo_sa  = (const float*)d_in[9];
    const float* wv_ca  = (const float*)d_in[12];
    const float* bv_ca  = (const float*)d_in[13];
    const float* wo_ca  = (const float*)d_in[14];
    const float* bo_ca  = (const float*)d_in[15];
    const float* ln3_g  = (const float*)d_in[16];
    const float* ln3_b  = (const float*)d_in[17];
    const float* w_ff1  = (const float*)d_in[18];
    const float* b_ff1  = (const float*)d_in[19];
    const float* w_ff2  = (const float*)d_in[20];
    const float* b_ff2  = (const float*)d_in[21];
    const float* lnoutg = (const float*)d_in[22];
    const float* lnoutb = (const float*)d_in[23];
    const float* wh1    = (const float*)d_in[24];
    const float* bh1    = (const float*)d_in[25];
    const float* lnh_g  = (const float*)d_in[26];
    const float* lnh_b  = (const float*)d_in[27];
    const float* wh2    = (const float*)d_in[28];
    const float* bh2    = (const float*)d_in[29];
    float* out = (float*)d_out;
    const int KBIG = 0x7fffffff;

    // ---- workspace layout (~70 MB, rewritten fully every call) ----
    char* wsp = (char*)d_ws;
    size_t off = 0;
    auto ALLOC = [&](size_t n) { char* r = wsp + off; off = (off + n + 255) & ~(size_t)255; return r; };
    u16* w_inT  = (u16*)ALLOC(512UL * 4096 * 2);
    u16* wff1t  = (u16*)ALLOC(2048UL * 512 * 2);
    u16* wff2t  = (u16*)ALLOC(512UL * 2048 * 2);
    u16* woT2   = (u16*)ALLOC(2UL * 512 * 512 * 2);  // [0]=woTca, [1]=woTsa
    u16* wv2b   = (u16*)ALLOC(2UL * 512 * 512 * 2);  // [0]=wv_ca, [1]=wv_sa
    u16* Wct    = (u16*)ALLOC(512UL * 1024 * 2);     // [n][k] k<512: ca, k>=512: sa
    u16* Wh1t   = (u16*)ALLOC(768UL * 512 * 2);
    u16* Wh2t   = (u16*)ALLOC(3UL * 896 * 256 * 2);
    float* bias_in = (float*)ALLOC(512 * 4);
    float* b_comb  = (float*)ALLOC(512 * 4);
    u16* h0   = (u16*)ALLOC(8192UL * 512 * 2);   // h0, later reused as h3
    u16* T    = (u16*)ALLOC(8192UL * 512 * 2);   // ln1 / ln3 / lnout output
    u16* hbuf = (u16*)ALLOC(8192UL * 512 * 2);   // h2
    u16* G    = (u16*)ALLOC(8192UL * 2048 * 2);  // FF intermediate; Z/Z2 alias
    u16* Z  = G;
    u16* Z2 = (u16*)((char*)G + 8192UL * 768 * 2);
    // split-K partial regions (alias buffers that are FREE at that stage):
    float* part1 = (float*)T;   // GEMM1: spans T+hbuf+G (3 x 16.78 MB) — all free
    float* part2 = (float*)G;   // attention: 2 x 16.78 MB in G — free
    const long PZS = 8192L * 512;

    // ---- weight prep ----
    cvt_f32_bf16<<<128, 256, 0, stream>>>(wv_ca, wv2b, 512 * 512 / 8);
    cvt_f32_bf16<<<128, 256, 0, stream>>>(wv_sa, wv2b + 512 * 512, 512 * 512 / 8);
    prep_bias_kernel<<<8, 256, 0, stream>>>(b_in, pos, bv_sa, wo_sa, bo_sa,
        bv_ca, wo_ca, bo_ca, bias_in, b_comb);
    transpose_kernel<<<dim3(16, 128), 256, 0, stream>>>(w_in, w_inT, 4096, 512);
    transpose_kernel<<<dim3(64, 16), 256, 0, stream>>>(w_ff1, wff1t, 512, 2048);
    transpose_kernel<<<dim3(16, 64), 256, 0, stream>>>(w_ff2, wff2t, 2048, 512);
    transpose_kernel<<<dim3(16, 16), 256, 0, stream>>>(wo_ca, woT2, 512, 512);
    transpose_kernel<<<dim3(16, 16), 256, 0, stream>>>(wo_sa, woT2 + 512 * 512, 512, 512);
    gather_wh1t<<<1536, 256, 0, stream>>>(wh1, Wh1t);
    gather_wh2t<<<2688, 256, 0, stream>>>(wh2, Wh2t);
    // Wct (z-batched): z=0 -> ca half (k<512), z=1 -> sa half (k>=512)
    gemm64<false, false, false, false, false><<<dim3(8, 4, 2), 256, 0, stream>>>(
        woT2, nullptr, KBIG, wv2b, nullptr, nullptr, 0, Wct,
        512, 512, 512, 1024, 512 * 512, 512 * 512, 0, 512, 0);

    // ---- main pipeline (m-tile on blockIdx.x everywhere) ----
    // GEMM1 split-K x3 (chunks 1376/1376/1344): partials, then reduce+bias
    gemm64<false, false, true, false, true><<<dim3(128, 4, 3), 256, 0, stream>>>(
        x, nullptr, KBIG, w_inT, nullptr, nullptr, 0, part1,
        4096, 4096, 4096, 512, 0, 0, 0, PZS, 1376);
    reduceK<3><<<4096, 256, 0, stream>>>(part1, PZS, bias_in, nullptr, h0);
    // T = ln1(h0)
    ln512_kernel<<<2048, 256, 0, stream>>>(h0, ln1_g, ln1_b, T);
    // attention split-K x2: [h0 | T] @ Wct -> partials in G; reduce fuses
    // +b_comb +h0 residual -> h2 (hbuf)
    gemm64<false, false, false, false, true><<<dim3(128, 4, 2), 256, 0, stream>>>(
        h0, T, 512, Wct, nullptr, nullptr, 0, part2,
        1024, 512, 1024, 512, 0, 0, 0, PZS, 512);
    reduceK<2><<<4096, 256, 0, stream>>>(part2, PZS, b_comb, h0, hbuf);
    // T = ln3(h2)
    ln512_kernel<<<2048, 256, 0, stream>>>(hbuf, ln3_g, ln3_b, T);
    // G = gelu(T @ w_ff1 + b_ff1)   [8192, 2048]
    gemm64<true, false, false, false, false><<<dim3(128, 16), 256, 0, stream>>>(
        T, nullptr, KBIG, wff1t, b_ff1, nullptr, 0, G,
        512, 512, 512, 2048, 0, 0, 0, 0, 0);
    // h3(=h0) = h2 + G @ w_ff2 + b_ff2
    gemm64<false, true, false, false, false><<<dim3(128, 4), 256, 0, stream>>>(
        G, nullptr, KBIG, wff2t, b_ff2, hbuf, 512, h0,
        2048, 2048, 2048, 512, 0, 0, 0, 0, 0);
    // T = lnout(h3)
    ln512_kernel<<<2048, 256, 0, stream>>>(h0, lnoutg, lnoutb, T);
    // Z = gelu(T @ Wh1 + bh1)   [8192, 768]
    gemm64<true, false, false, false, false><<<dim3(128, 6), 256, 0, stream>>>(
        T, nullptr, KBIG, Wh1t, bh1, nullptr, 0, Z,
        512, 512, 512, 768, 0, 0, 0, 0, 0);
    // Z2 = per-head LN(Z)
    lnh_kernel<<<6144, 256, 0, stream>>>(Z, lnh_g, lnh_b, Z2);
    // out[:, z*896:(z+1)*896] = Z2[:, z*256:+256] @ wh2[z] + bh2[z]  (f32, z-batched)
    gemm64<false, false, false, true, false><<<dim3(128, 7, 3), 256, 0, stream>>>(
        Z2, nullptr, KBIG, Wh2t, bh2, nullptr, 0, out,
        256, 768, 256, 2688, 256, 896 * 256, 896, 896, 0);
}